// Round 3
// baseline (313.763 us; speedup 1.0000x reference)
//
#include <hip/hip_runtime.h>
#include <stdint.h>

#define DDIM 256
#define BROWS 512
#define CCOLS 100000
#define NCHUNK 3125          // 100000 / 32 cols per block (exact)
#define MM 0.2f
#define SS 30.0f

typedef __attribute__((ext_vector_type(8))) short bf16x8;
typedef __attribute__((ext_vector_type(16))) float f32x16;

__device__ __forceinline__ float b2f(unsigned short u) {
    union { unsigned int i; float f; } v; v.i = ((unsigned int)u) << 16; return v.f;
}
__device__ __forceinline__ unsigned short f2b(float f) {
    union { float f; unsigned int i; } v; v.f = f;
    unsigned int r = v.i + 0x7FFFu + ((v.i >> 16) & 1u);   // round-nearest-even
    return (unsigned short)(r >> 16);
}

// --- L2-normalize rows of a [nrows, 256] fp32 matrix into bf16 (one wave per row) ---
__global__ void norm_rows(const float* __restrict__ src, unsigned short* __restrict__ dst, int nrows) {
    int row = blockIdx.x * (blockDim.x >> 6) + (threadIdx.x >> 6);
    if (row >= nrows) return;
    int lane = threadIdx.x & 63;
    float4 v = ((const float4*)(src + (size_t)row * DDIM))[lane];
    float ss = v.x * v.x + v.y * v.y + v.z * v.z + v.w * v.w;
#pragma unroll
    for (int m = 1; m <= 32; m <<= 1) ss += __shfl_xor(ss, m);
    float inv = 1.0f / fmaxf(sqrtf(ss), 1e-12f);
    ushort4 o;
    o.x = f2b(v.x * inv); o.y = f2b(v.y * inv); o.z = f2b(v.z * inv); o.w = f2b(v.w * inv);
    ((ushort4*)(dst + (size_t)row * DDIM))[lane] = o;
}

// --- fused GEMM (cos = xn . wn^T) + exp + per-row partial sums ---
// block: 512 rows x 32 cols; wave: 128 rows x 32 cols, 4 row-tiles of 32x32, K=256 in 16 steps.
// B-frags held in registers (reused across 4 row-tiles); A streamed (x hot in L1/L2).
__global__ __launch_bounds__(256) void gemm_lse(const unsigned short* __restrict__ xn,
                                                const unsigned short* __restrict__ wn,
                                                float* __restrict__ sums /* [512][NCHUNK] */) {
    int p    = blockIdx.x;            // column chunk
    int lane = threadIdx.x & 63;
    int wave = threadIdx.x >> 6;
    int colh = lane & 31;             // col within 32-wide chunk (B operand n, D operand col)
    int kg   = (lane >> 5) * 8;       // k sub-group offset (same mapping for A and B)

    size_t col = (size_t)p * 32 + colh;
    const unsigned short* wbase = wn + col * DDIM + kg;
    bf16x8 bfrag[16];
#pragma unroll
    for (int kk = 0; kk < 16; ++kk)
        bfrag[kk] = *(const bf16x8*)(wbase + kk * 16);

    int rbase = wave * 128 + 4 * (lane >> 5);   // C/D layout: row = (reg&3) + 8*(reg>>2) + 4*(lane>>5)
    const unsigned short* xbase = xn + (size_t)(wave * 128 + colh) * DDIM + kg; // A operand: row = lane&31

#pragma unroll
    for (int rt = 0; rt < 4; ++rt) {
        f32x16 acc;
#pragma unroll
        for (int i = 0; i < 16; ++i) acc[i] = 0.0f;
        const unsigned short* xr = xbase + (size_t)rt * 32 * DDIM;
#pragma unroll
        for (int kk = 0; kk < 16; ++kk) {
            bf16x8 af = *(const bf16x8*)(xr + kk * 16);
            acc = __builtin_amdgcn_mfma_f32_32x32x16_bf16(af, bfrag[kk], acc, 0, 0, 0);
        }
        // epilogue: logits = 30*cos (no penalties here; corrected in finalize), exp, col-reduce
#pragma unroll
        for (int r = 0; r < 16; ++r) {
            float e = __expf(SS * acc[r]);
#pragma unroll
            for (int m = 1; m <= 16; m <<= 1) e += __shfl_xor(e, m);
            if (colh == 0) {
                int row = rbase + rt * 32 + (r & 3) + 8 * (r >> 2);
                sums[(size_t)row * NCHUNK + p] = e;
            }
        }
    }
}

// --- reduce the per-chunk partials into one sum per row ---
__global__ void row_reduce(const float* __restrict__ sums, float* __restrict__ rowsum) {
    int b = blockIdx.x;
    float s = 0.0f;
    for (int i = threadIdx.x; i < NCHUNK; i += 256) s += sums[(size_t)b * NCHUNK + i];
#pragma unroll
    for (int m = 1; m <= 32; m <<= 1) s += __shfl_xor(s, m);
    __shared__ float ls[4];
    if ((threadIdx.x & 63) == 0) ls[threadIdx.x >> 6] = s;
    __syncthreads();
    if (threadIdx.x == 0) rowsum[b] = ls[0] + ls[1] + ls[2] + ls[3];
}

// --- per-row: recompute 4 special cos, apply scatter corrections, lse, weighted CE ---
__global__ void finalize(const unsigned short* __restrict__ xn,
                         const unsigned short* __restrict__ wn,
                         const float* __restrict__ rowsum,
                         const float* __restrict__ lamp,
                         const int* __restrict__ t1, const int* __restrict__ p1,
                         const int* __restrict__ t2, const int* __restrict__ p2,
                         float* __restrict__ out) {
    int b = blockIdx.x * (blockDim.x >> 6) + (threadIdx.x >> 6);   // one wave per row
    int lane = threadIdx.x & 63;
    ushort4 xr = ((const ushort4*)(xn + (size_t)b * DDIM))[lane];
    float x0 = b2f(xr.x), x1 = b2f(xr.y), x2 = b2f(xr.z), x3 = b2f(xr.w);
    int idx[4] = { t1[b], p1[b], t2[b], p2[b] };
    float cosv[4];
#pragma unroll
    for (int k = 0; k < 4; ++k) {
        ushort4 wr = ((const ushort4*)(wn + (size_t)idx[k] * DDIM))[lane];
        float s = x0 * b2f(wr.x) + x1 * b2f(wr.y) + x2 * b2f(wr.z) + x3 * b2f(wr.w);
#pragma unroll
        for (int m = 1; m <= 32; m <<= 1) s += __shfl_xor(s, m);
        cosv[k] = s;
    }
    if (lane == 0) {
        // final value at column idx[k]; overwrite order t1(scaled), p1, t2, p2 => priority p2>t2>p1>t1
        auto finalv = [&](int k) -> float {
            int c = idx[k]; float cv = cosv[k];
            if (c == idx[3]) return cv - MM;
            if (c == idx[2]) return cv - MM;
            if (c == idx[1]) return cv - MM;
            return SS * (cv - MM);          // only reachable for k==0 (targets1)
        };
        float delta = 0.0f;
#pragma unroll
        for (int k = 0; k < 4; ++k) {
            bool first = true;
            for (int j = 0; j < k; ++j) if (idx[j] == idx[k]) first = false;
            if (first) delta += __expf(finalv(k)) - __expf(SS * cosv[k]);
        }
        float lse = logf(rowsum[b] + delta);
        float lam = lamp[0];
        float lossb = lam        * (0.2f * (lse - finalv(0)) + 0.8f * (lse - finalv(1)))
                    + (1.f - lam) * (0.2f * (lse - finalv(2)) + 0.8f * (lse - finalv(3)));
        atomicAdd(out, lossb * (1.0f / 512.0f));
    }
}

extern "C" void kernel_launch(void* const* d_in, const int* in_sizes, int n_in,
                              void* d_out, int out_size, void* d_ws, size_t ws_size,
                              hipStream_t stream) {
    const float* x   = (const float*)d_in[0];
    const float* w   = (const float*)d_in[1];
    const float* lam = (const float*)d_in[2];
    const int* t1    = (const int*)d_in[3];
    const int* p1    = (const int*)d_in[4];
    const int* t2    = (const int*)d_in[5];
    const int* p2    = (const int*)d_in[6];
    float* out = (float*)d_out;

    char* ws = (char*)d_ws;
    unsigned short* xn = (unsigned short*)ws;                          // 512*256*2   = 262144 B
    unsigned short* wn = (unsigned short*)(ws + 262144);               // 100000*256*2 = 51200000 B
    float* sums   = (float*)(ws + 262144 + 51200000);                  // 512*3125*4  = 6400000 B
    float* rowsum = (float*)(ws + 262144 + 51200000 + 6400000);        // 512*4 B

    hipMemsetAsync(out, 0, sizeof(float), stream);
    norm_rows<<<128,   256, 0, stream>>>(x, xn, BROWS);
    norm_rows<<<25000, 256, 0, stream>>>(w, wn, CCOLS);
    gemm_lse<<<NCHUNK, 256, 0, stream>>>(xn, wn, sums);
    row_reduce<<<BROWS, 256, 0, stream>>>(sums, rowsum);
    finalize<<<128, 256, 0, stream>>>(xn, wn, rowsum, lam, t1, p1, t2, p2, out);
}

// Round 4
// 305.476 us; speedup vs baseline: 1.0271x; 1.0271x over previous
//
#include <hip/hip_runtime.h>
#include <stdint.h>

#define DDIM 256
#define BROWS 512
#define CCOLS 100000
#define NBLK 782            // ceil(100000 / 128) column-chunks
#define NCH  (NBLK * 4)     // partial row-sums per row (4 col-groups per block)
#define MM 0.2f
#define SS 30.0f

typedef __attribute__((ext_vector_type(8))) short bf16x8;
typedef __attribute__((ext_vector_type(16))) float f32x16;

__device__ __forceinline__ float b2f(unsigned short u) {
    union { unsigned int i; float f; } v; v.i = ((unsigned int)u) << 16; return v.f;
}
__device__ __forceinline__ unsigned short f2b(float f) {
    union { float f; unsigned int i; } v; v.f = f;
    unsigned int r = v.i + 0x7FFFu + ((v.i >> 16) & 1u);   // RNE
    return (unsigned short)(r >> 16);
}

// K1: normalize x rows, write bf16 in MFMA B-fragment layout:
// xpack[g 16][kk 16][lane 64] x 8 bf16, element (g*32+n, kk*16+hi*8+j) at lane hi*32+n elem j.
__global__ void norm_x_pack(const float* __restrict__ x, unsigned short* __restrict__ xp) {
    int row = blockIdx.x * 4 + (threadIdx.x >> 6);   // grid 128 x 256 => 512 rows
    int ln  = threadIdx.x & 63;
    float4 v = ((const float4*)(x + (size_t)row * DDIM))[ln];   // k = 4*ln .. +3
    float ss = v.x * v.x + v.y * v.y + v.z * v.z + v.w * v.w;
#pragma unroll
    for (int m = 1; m <= 32; m <<= 1) ss += __shfl_xor(ss, m);
    float inv = 1.0f / fmaxf(sqrtf(ss), 1e-12f);
    int g = row >> 5, n = row & 31;
    int kk = ln >> 2, hi = (ln >> 1) & 1;
    size_t uoff = ((size_t)(g * 16 + kk) * 64 + hi * 32 + n) * 8 + (ln & 1) * 4;
    ushort4 o;
    o.x = f2b(v.x * inv); o.y = f2b(v.y * inv); o.z = f2b(v.z * inv); o.w = f2b(v.w * inv);
    *(ushort4*)(xp + uoff) = o;   // 8 B store
}

// K2: fused w-normalize + GEMM + exp + per-(row, col-group) partial sums.
// grid NBLK blocks x 512 thr (8 waves). Block tile: 512 rows x 128 cols.
// Phase A: w fp32 -> normalized bf16 frags in LDS [kk][hi][col] x 16 B (64 KB).
// Phase B: wave (rg = w>>2 in {0,1}, cg = w&3): 256 rows x 32 cols, R=8 row-subtiles.
//   mfma(w_frag, x_frag): D lane = x-row (n), D regs = w-col -> exp+sum is in-lane.
__global__ __launch_bounds__(512, 2) void fused_gemm(const float* __restrict__ w,
                                                     const unsigned short* __restrict__ xp,
                                                     float* __restrict__ sums) {
    __shared__ unsigned short wlds[16 * 2 * 128 * 8];   // 64 KB
    int blk = blockIdx.x, t = threadIdx.x;
    int cbase = blk * 128;

    // ---- Phase A: 4 threads per col, 64 floats each ----
    {
        int col = t >> 2, q = t & 3;
        int gcol = cbase + col;
        float f[64];
        if (gcol < CCOLS) {
            const float4* src = (const float4*)(w + (size_t)gcol * DDIM + q * 64);
#pragma unroll
            for (int i = 0; i < 16; ++i) {
                float4 v = src[i];
                f[i * 4 + 0] = v.x; f[i * 4 + 1] = v.y; f[i * 4 + 2] = v.z; f[i * 4 + 3] = v.w;
            }
        } else {
#pragma unroll
            for (int i = 0; i < 64; ++i) f[i] = 0.0f;
        }
        float ss = 0.0f;
#pragma unroll
        for (int i = 0; i < 64; ++i) ss += f[i] * f[i];
        ss += __shfl_xor(ss, 1); ss += __shfl_xor(ss, 2);   // 4 lanes share a col
        float inv = 1.0f / fmaxf(sqrtf(ss), 1e-12f);
#pragma unroll
        for (int s = 0; s < 8; ++s) {
            int kk = q * 4 + (s >> 1), hi = s & 1;
            int o = (s >> 1) * 16 + (s & 1) * 8;   // local float base, elems o..o+7
            unsigned int u0 = (unsigned)f2b(f[o+0]*inv) | ((unsigned)f2b(f[o+1]*inv) << 16);
            unsigned int u1 = (unsigned)f2b(f[o+2]*inv) | ((unsigned)f2b(f[o+3]*inv) << 16);
            unsigned int u2 = (unsigned)f2b(f[o+4]*inv) | ((unsigned)f2b(f[o+5]*inv) << 16);
            unsigned int u3 = (unsigned)f2b(f[o+6]*inv) | ((unsigned)f2b(f[o+7]*inv) << 16);
            uint4 pk = make_uint4(u0, u1, u2, u3);
            *(uint4*)(wlds + (size_t)((kk * 2 + hi) * 128 + col) * 8) = pk;
        }
    }
    __syncthreads();

    // ---- Phase B ----
    int wv = t >> 6, lane = t & 63;
    int rg = wv >> 2, cg = wv & 3;
    int m = lane & 31, hi = lane >> 5;

    f32x16 acc[8];
#pragma unroll
    for (int rs = 0; rs < 8; ++rs)
#pragma unroll
        for (int i = 0; i < 16; ++i) acc[rs][i] = 0.0f;

#pragma unroll 4
    for (int kk = 0; kk < 16; ++kk) {
        bf16x8 wf = *(const bf16x8*)(wlds + (size_t)((kk * 2 + hi) * 128 + cg * 32 + m) * 8);
#pragma unroll
        for (int rs = 0; rs < 8; ++rs) {
            bf16x8 xf = *(const bf16x8*)(xp + ((size_t)((rg * 8 + rs) * 16 + kk) * 64 + lane) * 8);
            acc[rs] = __builtin_amdgcn_mfma_f32_32x32x16_bf16(wf, xf, acc[rs], 0, 0, 0);
        }
    }

    // epilogue: e = exp(S*cos), in-lane sum over this lane's 16 w-cols, pair-sum across hi.
    int colb = cbase + cg * 32;
#pragma unroll
    for (int rs = 0; rs < 8; ++rs) {
        float p = 0.0f;
#pragma unroll
        for (int r = 0; r < 16; ++r) {
            int cl = (r & 3) + 8 * (r >> 2) + 4 * hi;   // D-row = w-col within 32
            float e = __expf(SS * acc[rs][r]);
            p += (colb + cl < CCOLS) ? e : 0.0f;
        }
        p += __shfl_xor(p, 32);
        if (hi == 0) {
            int row = rg * 256 + rs * 32 + m;           // D-col = x-row
            sums[(size_t)row * NCH + blk * 4 + cg] = p;
        }
    }
}

// K3: per-row partial-sum reduce + special-column corrections + weighted CE.
__global__ void reduce_finalize(const float* __restrict__ sums,
                                const float* __restrict__ x, const float* __restrict__ w,
                                const float* __restrict__ lamp,
                                const int* __restrict__ t1, const int* __restrict__ p1,
                                const int* __restrict__ t2, const int* __restrict__ p2,
                                float* __restrict__ out) {
    int b = blockIdx.x, t = threadIdx.x;
    float s = 0.0f;
    for (int i = t; i < NCH; i += 256) s += sums[(size_t)b * NCH + i];
#pragma unroll
    for (int m = 1; m <= 32; m <<= 1) s += __shfl_xor(s, m);
    __shared__ float ls[4];
    if ((t & 63) == 0) ls[t >> 6] = s;
    __syncthreads();
    if (t < 64) {
        int ln = t;
        float rowsum = ls[0] + ls[1] + ls[2] + ls[3];
        float4 xv = ((const float4*)(x + (size_t)b * DDIM))[ln];
        float ssx = xv.x*xv.x + xv.y*xv.y + xv.z*xv.z + xv.w*xv.w;
#pragma unroll
        for (int m = 1; m <= 32; m <<= 1) ssx += __shfl_xor(ssx, m);
        float xinv = 1.0f / fmaxf(sqrtf(ssx), 1e-12f);
        int idx[4] = { t1[b], p1[b], t2[b], p2[b] };
        float cosv[4];
#pragma unroll
        for (int k = 0; k < 4; ++k) {
            float4 wv = ((const float4*)(w + (size_t)idx[k] * DDIM))[ln];
            float d  = xv.x*wv.x + xv.y*wv.y + xv.z*wv.z + xv.w*wv.w;
            float sw = wv.x*wv.x + wv.y*wv.y + wv.z*wv.z + wv.w*wv.w;
#pragma unroll
            for (int m = 1; m <= 32; m <<= 1) { d += __shfl_xor(d, m); sw += __shfl_xor(sw, m); }
            cosv[k] = d * xinv / fmaxf(sqrtf(sw), 1e-12f);
        }
        if (ln == 0) {
            // overwrite order t1(S-scaled), p1, t2, p2 => priority p2 > t2 > p1 > t1
            auto finalv = [&](int k) -> float {
                int c = idx[k]; float cv = cosv[k];
                if (c == idx[3]) return cv - MM;
                if (c == idx[2]) return cv - MM;
                if (c == idx[1]) return cv - MM;
                return SS * (cv - MM);
            };
            float delta = 0.0f;
#pragma unroll
            for (int k = 0; k < 4; ++k) {
                bool first = true;
                for (int j = 0; j < k; ++j) if (idx[j] == idx[k]) first = false;
                if (first) delta += __expf(finalv(k)) - __expf(SS * cosv[k]);
            }
            float lse = logf(rowsum + delta);
            float lam = lamp[0];
            float lossb = lam          * (0.2f * (lse - finalv(0)) + 0.8f * (lse - finalv(1)))
                        + (1.0f - lam) * (0.2f * (lse - finalv(2)) + 0.8f * (lse - finalv(3)));
            atomicAdd(out, lossb * (1.0f / 512.0f));
        }
    }
}

extern "C" void kernel_launch(void* const* d_in, const int* in_sizes, int n_in,
                              void* d_out, int out_size, void* d_ws, size_t ws_size,
                              hipStream_t stream) {
    const float* x   = (const float*)d_in[0];
    const float* w   = (const float*)d_in[1];
    const float* lam = (const float*)d_in[2];
    const int* t1    = (const int*)d_in[3];
    const int* p1    = (const int*)d_in[4];
    const int* t2    = (const int*)d_in[5];
    const int* p2    = (const int*)d_in[6];
    float* out = (float*)d_out;

    char* ws = (char*)d_ws;
    unsigned short* xpack = (unsigned short*)ws;            // 512*256*2 = 262144 B (frag layout)
    float* sums = (float*)(ws + 262144);                    // 512*NCH*4 = 6,406,144 B

    hipMemsetAsync(out, 0, sizeof(float), stream);
    norm_x_pack<<<128, 256, 0, stream>>>(x, xpack);
    fused_gemm<<<NBLK, 512, 0, stream>>>(w, xpack, sums);
    reduce_finalize<<<BROWS, 256, 0, stream>>>(sums, x, w, lam, t1, p1, t2, p2, out);
}

// Round 7
// 277.806 us; speedup vs baseline: 1.1294x; 1.0996x over previous
//
#include <hip/hip_runtime.h>
#include <stdint.h>

#define DDIM 256
#define BROWS 512
#define CCOLS 100000
#define CGRP 3125            // 32-col groups that exist
#define CGRP_PAD 3128        // 782 blocks * 4 groups (tail zero-padded)
#define NBLKC 782            // col-blocks of 128
#define MM 0.2f
#define SS 30.0f

typedef __attribute__((ext_vector_type(8))) short bf16x8;
typedef __attribute__((ext_vector_type(16))) float f32x16;

__device__ __forceinline__ unsigned short f2b(float f) {
    union { float f; unsigned int i; } v; v.f = f;
    unsigned int r = v.i + 0x7FFFu + ((v.i >> 16) & 1u);   // RNE
    return (unsigned short)(r >> 16);
}

// K1: normalize x rows -> bf16 MFMA B-fragment layout.
// xpack[g 16][kk 16][hi*32+row 64] x 8 bf16: element (g*32+n, kk*16+hi*8+j) at lane hi*32+n.
__global__ void norm_x_pack(const float* __restrict__ x, unsigned short* __restrict__ xp) {
    int row = blockIdx.x * 4 + (threadIdx.x >> 6);   // 128 blocks x 256 thr = 512 rows
    int l   = threadIdx.x & 63;
    float4 v = ((const float4*)(x + (size_t)row * DDIM))[l];   // k = 4l..4l+3
    float ss = v.x*v.x + v.y*v.y + v.z*v.z + v.w*v.w;
#pragma unroll
    for (int m = 1; m <= 32; m <<= 1) ss += __shfl_xor(ss, m);
    float inv = 1.0f / fmaxf(sqrtf(ss), 1e-12f);
    int g = row >> 5, n = row & 31;
    int kk = l >> 2, hi = (l >> 1) & 1;
    size_t uoff = ((size_t)(g * 16 + kk) * 64 + hi * 32 + n) * 8 + (l & 1) * 4;
    ushort4 o;
    o.x = f2b(v.x*inv); o.y = f2b(v.y*inv); o.z = f2b(v.z*inv); o.w = f2b(v.w*inv);
    *(ushort4*)(xp + uoff) = o;
}

// K2: normalize w rows -> bf16 fragment layout, fully coalesced in and out.
// Block: 32 w-rows (16 KB out). Wave wv, iter i handles row c = i*4+wv entirely
// (lane l holds k=4l..4l+3 -> contiguous 1KB wave read). LDS-staged so the
// global write is pure 16B-coalesced.
__global__ __launch_bounds__(256) void norm_w_pack(const float* __restrict__ w,
                                                   unsigned short* __restrict__ wp) {
    __shared__ unsigned short wlds[8192];   // 16 KB = this block's wpack tile
    int blk = blockIdx.x;                   // 3125
    int t = threadIdx.x, wv = t >> 6, l = t & 63;
    const float* wb = w + (size_t)blk * 32 * DDIM;
    int kk = l >> 2, hi = (l >> 1) & 1;
#pragma unroll
    for (int i = 0; i < 8; ++i) {
        int c = i * 4 + wv;
        float4 v = *(const float4*)(wb + (size_t)c * DDIM + 4 * l);
        float ss = v.x*v.x + v.y*v.y + v.z*v.z + v.w*v.w;
#pragma unroll
        for (int m = 1; m <= 32; m <<= 1) ss += __shfl_xor(ss, m);
        float inv = 1.0f / fmaxf(sqrtf(ss), 1e-12f);
        ushort4 o;
        o.x = f2b(v.x*inv); o.y = f2b(v.y*inv); o.z = f2b(v.z*inv); o.w = f2b(v.w*inv);
        *(ushort4*)(wlds + ((size_t)((kk * 2 + hi) * 32 + c)) * 8 + (l & 1) * 4) = o;
    }
    __syncthreads();
    const uint4* src = (const uint4*)wlds;
    uint4* dst = (uint4*)(wp + (size_t)blk * 8192);   // 8192 shorts per block
#pragma unroll
    for (int j = 0; j < 4; ++j) dst[j * 256 + t] = src[j * 256 + t];
}

// K3: GEMM from pre-packed fragments + exp + in-lane col-sum + per-row atomic.
// grid (782 col-blocks, 4 row-groups) x 256 thr. Wave cg: 128 rows x 32 cols, acc[4].
// All loads are 1KB coalesced wave loads; no staging, no K-loop barriers.
__global__ __launch_bounds__(256, 3) void gemm_lse(const unsigned short* __restrict__ wp,
                                                   const unsigned short* __restrict__ xp,
                                                   float* __restrict__ rowacc) {
    __shared__ float red[4][128];
    int blkc = blockIdx.x, rgrp = blockIdx.y;
    int t = threadIdx.x, cg = t >> 6, lane = t & 63;
    int m = lane & 31, hi = lane >> 5;

    const unsigned short* wbase = wp + (size_t)(blkc * 4 + cg) * 8192 + lane * 8;
    const unsigned short* xbase = xp + (size_t)(rgrp * 4) * 8192 + lane * 8;

    f32x16 acc[4];
#pragma unroll
    for (int rs = 0; rs < 4; ++rs)
#pragma unroll
        for (int i = 0; i < 16; ++i) acc[rs][i] = 0.0f;

#pragma unroll
    for (int kk = 0; kk < 16; ++kk) {
        bf16x8 wf = *(const bf16x8*)(wbase + kk * 512);
#pragma unroll
        for (int rs = 0; rs < 4; ++rs) {
            bf16x8 xf = *(const bf16x8*)(xbase + rs * 8192 + kk * 512);
            acc[rs] = __builtin_amdgcn_mfma_f32_32x32x16_bf16(wf, xf, acc[rs], 0, 0, 0);
        }
    }

    int colb = blkc * 128 + cg * 32;
#pragma unroll
    for (int rs = 0; rs < 4; ++rs) {
        float p = 0.0f;
#pragma unroll
        for (int r = 0; r < 16; ++r) {
            int cl = (r & 3) + 8 * (r >> 2) + 4 * hi;   // D-row = w-col within 32
            float e = __expf(SS * acc[rs][r]);
            p += (colb + cl < CCOLS) ? e : 0.0f;
        }
        p += __shfl_xor(p, 32);
        if (hi == 0) red[cg][rs * 32 + m] = p;          // D-col = x-row = m
    }
    __syncthreads();
    if (t < 128) {
        float s = red[0][t] + red[1][t] + red[2][t] + red[3][t];
        atomicAdd(&rowacc[rgrp * 128 + t], s);
    }
}

// K4: per-row special-column corrections (fp32-exact) + lse + weighted CE.
__global__ void finalize(const float* __restrict__ rowacc,
                         const float* __restrict__ x, const float* __restrict__ w,
                         const float* __restrict__ lamp,
                         const int* __restrict__ t1, const int* __restrict__ p1,
                         const int* __restrict__ t2, const int* __restrict__ p2,
                         float* __restrict__ out) {
    int b  = blockIdx.x * 4 + (threadIdx.x >> 6);   // 128 blocks x 256 thr, wave per row
    int ln = threadIdx.x & 63;
    float4 xv = ((const float4*)(x + (size_t)b * DDIM))[ln];
    float ssx = xv.x*xv.x + xv.y*xv.y + xv.z*xv.z + xv.w*xv.w;
#pragma unroll
    for (int m = 1; m <= 32; m <<= 1) ssx += __shfl_xor(ssx, m);
    float xinv = 1.0f / fmaxf(sqrtf(ssx), 1e-12f);
    int idx[4] = { t1[b], p1[b], t2[b], p2[b] };
    float cosv[4];
#pragma unroll
    for (int k = 0; k < 4; ++k) {
        float4 wv = ((const float4*)(w + (size_t)idx[k] * DDIM))[ln];
        float d  = xv.x*wv.x + xv.y*wv.y + xv.z*wv.z + xv.w*wv.w;
        float sw = wv.x*wv.x + wv.y*wv.y + wv.z*wv.z + wv.w*wv.w;
#pragma unroll
        for (int m = 1; m <= 32; m <<= 1) { d += __shfl_xor(d, m); sw += __shfl_xor(sw, m); }
        cosv[k] = d * xinv / fmaxf(sqrtf(sw), 1e-12f);
    }
    if (ln == 0) {
        // overwrite order t1(S-scaled), p1, t2, p2 => priority p2 > t2 > p1 > t1
        auto finalv = [&](int k) -> float {
            int c = idx[k]; float cv = cosv[k];
            if (c == idx[3]) return cv - MM;
            if (c == idx[2]) return cv - MM;
            if (c == idx[1]) return cv - MM;
            return SS * (cv - MM);
        };
        float delta = 0.0f;
#pragma unroll
        for (int k = 0; k < 4; ++k) {
            bool first = true;
            for (int j = 0; j < k; ++j) if (idx[j] == idx[k]) first = false;
            if (first) delta += __expf(finalv(k)) - __expf(SS * cosv[k]);
        }
        float lse = logf(rowacc[b] + delta);
        float lam = lamp[0];
        float lossb = lam          * (0.2f * (lse - finalv(0)) + 0.8f * (lse - finalv(1)))
                    + (1.0f - lam) * (0.2f * (lse - finalv(2)) + 0.8f * (lse - finalv(3)));
        atomicAdd(out, lossb * (1.0f / 512.0f));
    }
}

extern "C" void kernel_launch(void* const* d_in, const int* in_sizes, int n_in,
                              void* d_out, int out_size, void* d_ws, size_t ws_size,
                              hipStream_t stream) {
    const float* x   = (const float*)d_in[0];
    const float* w   = (const float*)d_in[1];
    const float* lam = (const float*)d_in[2];
    const int* t1    = (const int*)d_in[3];
    const int* p1    = (const int*)d_in[4];
    const int* t2    = (const int*)d_in[5];
    const int* p2    = (const int*)d_in[6];
    float* out = (float*)d_out;

    char* ws = (char*)d_ws;
    unsigned short* xpack = (unsigned short*)ws;                 // 512*256*2      =   262,144 B
    unsigned short* wpack = (unsigned short*)(ws + 262144);      // 3128*16384     = 51,249,152 B
    float* rowacc = (float*)(ws + 262144 + 51249152);            // 512*4 B

    hipMemsetAsync(out, 0, sizeof(float), stream);
    hipMemsetAsync(rowacc, 0, BROWS * sizeof(float), stream);
    // zero the 3 padded wpack tail groups (cols 100000..100095): cos=0, masked in epilogue
    hipMemsetAsync((char*)wpack + (size_t)CGRP * 16384, 0, (CGRP_PAD - CGRP) * 16384, stream);

    norm_x_pack<<<128, 256, 0, stream>>>(x, xpack);
    norm_w_pack<<<CGRP, 256, 0, stream>>>(w, wpack);
    gemm_lse<<<dim3(NBLKC, 4), 256, 0, stream>>>(wpack, xpack, rowacc);
    finalize<<<128, 256, 0, stream>>>(rowacc, x, w, lam, t1, p1, t2, p2, out);
}